// Round 10
// baseline (277.037 us; speedup 1.0000x reference)
//
#include <hip/hip_runtime.h>
#include <stdint.h>

// GCN layer: out = prelu(W @ segsum(A_val * h[A_col] -> A_row) + b, act_a)
//            h   = prelu(Wr @ AX + br, g_a)
// spmm (R1/R7 kernel) AT its random-line fetch ceiling: ~79us, beyond-L2
// fetch pinned 2.0-2.25 TB/s across 4 structures (R10); h-miss ~165MB ==
// compulsory floor (8 XCDs x 86% col coverage x 25.6MB). Failures: R8
// global-atomic scatter; R11 threadfence scan (device fence = XCD L2 flush
// per block); R13 64-block scatter. R14 WIN 266.7 (X-staging dropped,
// scan2 inlined). R15 WIN 250.2 (GEMM rides scatter dispatch; shfl scan).
// R16: kill the hidden strided-4B traffic in the [b][blk] hist layout:
//  - hist_g TRANSPOSED to [blk][bucket]: hist writeout + scatter cursor-
//    init become contiguous rows (each was ~51MB RFO for 3.2MB logical);
//    NOTE: unlike R11's failed transpose, blocks here own whole ROWS (no
//    4B cross-XCD interleave) and there are no fences.
//  - scan1_tile: 49 blocks x 64 buckets, LDS tile (coalesced load ->
//    in-LDS segmented scan -> coalesced writeback) pays the transpose in
//    LDS, not DRAM.
//  - scatter edge stores nontemporal (random 8B; consumed from L3 later).

typedef _Float16 half8 __attribute__((ext_vector_type(8)));
typedef _Float16 half4 __attribute__((ext_vector_type(4)));
typedef _Float16 half2v __attribute__((ext_vector_type(2)));
typedef float floatx4 __attribute__((ext_vector_type(4)));

#define LDK 136        // GEMM LDS row stride in halfs: 128 + 8
#define SHIFT 5        // 32 rows per bucket
#define NBMAX 3200     // >= ceil(100000/32) = 3125
#define NBLK 256       // hist/scatter chunks
#define SCT 1024       // hist/scatter threads per block
#define CAP 1024       // LDS edge capacity per sort chunk (max bucket ~650 expected)
#define SCANB 64       // buckets per scan1_tile block
#define NBP 3136       // padded bucket count (49 * 64)

// ---------------- hist: per-chunk bucket histogram ----------------
// Layout hist_g[blk][bucket] -> writeout is a contiguous 12.5KB row.
// Block 0 also converts W fp32 -> f16 (consumed 2 dispatches later).
__global__ __launch_bounds__(SCT)
void bucket_hist(const int* __restrict__ rows, int* __restrict__ hist_g,
                 int E, int chunk, int NB,
                 const float* __restrict__ W, _Float16* __restrict__ W16)
{
    __shared__ int lh[NBMAX];
    int tid = threadIdx.x, blk = blockIdx.x;
    if (blk == 0) {
#pragma unroll
        for (int j = 0; j < 16; ++j) W16[tid + j * 1024] = (_Float16)W[tid + j * 1024];
    }
    for (int i = tid; i < NB; i += SCT) lh[i] = 0;
    __syncthreads();
    int s = blk * chunk, e = min(E, s + chunk);
    for (int i = s + tid; i < e; i += SCT)
        atomicAdd(&lh[rows[i] >> SHIFT], 1);
    __syncthreads();
    for (int b = tid; b < NB; b += SCT)
        hist_g[blk * NBP + b] = lh[b];           // contiguous row write
}

// ---------------- scan1_tile: transpose-in-LDS per-bucket chunk scan -------
// Block handles 64 buckets: loads the 256(chunks) x 64(buckets) tile with
// coalesced row reads, does a segmented exclusive scan down each bucket
// column in LDS, writes back coalesced. tot[b] = bucket total.
__global__ __launch_bounds__(1024)
void scan1_tile(int* __restrict__ hist_g, int* __restrict__ tot, int NB)
{
    __shared__ int tile[NBLK][SCANB + 1];        // 66.6KB, +1 pad vs bank hits
    __shared__ int segsum[SCANB][16];
    const int tid = threadIdx.x;
    const int b0  = blockIdx.x * SCANB;

#pragma unroll
    for (int j = 0; j < 16; ++j) {               // coalesced load
        int lin = tid + j * 1024;
        int r = lin >> 6, c = lin & 63;
        int gb = b0 + c;
        tile[r][c] = (gb < NB) ? hist_g[r * NBP + gb] : 0;
    }
    __syncthreads();

    const int c = tid >> 4, seg = tid & 15;      // 64 buckets x 16 segments
    int s = 0;
#pragma unroll
    for (int k = 0; k < 16; ++k) {               // exclusive within segment
        int r = seg * 16 + k;
        int v = tile[r][c];
        tile[r][c] = s;
        s += v;
    }
    segsum[c][seg] = s;
    __syncthreads();
    if (seg == 0) {                              // scan the 16 segment sums
        int run = 0;
#pragma unroll
        for (int k = 0; k < 16; ++k) { int v = segsum[c][k]; segsum[c][k] = run; run += v; }
        int gb = b0 + c;
        if (gb < NB) tot[gb] = run;              // bucket total
    }
    __syncthreads();
    {
        int base = segsum[c][seg];
#pragma unroll
        for (int k = 0; k < 16; ++k) tile[seg * 16 + k][c] += base;
    }
    __syncthreads();

#pragma unroll
    for (int j = 0; j < 16; ++j) {               // coalesced writeback
        int lin = tid + j * 1024;
        int r = lin >> 6, cc = lin & 63;
        int gb = b0 + cc;
        if (gb < NB) hist_g[r * NBP + gb] = tile[r][cc];
    }
}

// ------ fused scatter + GEMM1 (1024-thr blocks) ----------------------------
// blocks [0,NBLK): scatter with inlined tot-scan (R14-proven); cursor init
// now reads a contiguous hist_g row; edge stores nontemporal. blocks
// [NBLK,NBLK+gemmB): h = prelu(AX@Wr^T+br), 16 waves/block (R15-proven).
__global__ __launch_bounds__(1024, 4)
void scatter_gemm(const int* __restrict__ rows, const int* __restrict__ cols,
                  const float* __restrict__ vals, const int* __restrict__ tot,
                  const int* __restrict__ hist_g, uint2* __restrict__ edges,
                  int* __restrict__ bkt_ptr, int E, int chunk, int NB,
                  const float* __restrict__ X, const float* __restrict__ Wr,
                  const float* __restrict__ bias, const float* __restrict__ alpha_p,
                  _Float16* __restrict__ out, int N)
{
    __shared__ _Float16 Ws[128 * LDK];   // 34.8KB; scatter aliases a prefix
    const int tid = threadIdx.x;

    if (blockIdx.x < NBLK) {
        // ---------------- scatter path ----------------
        int* sd  = (int*)Ws;                     // [SCT]      4KB
        int* cur = (int*)Ws + SCT;               // [NBMAX]   12.8KB
        const int blk = blockIdx.x;

        int v[4]; int s = 0;
#pragma unroll
        for (int j = 0; j < 4; ++j) {
            int idx = tid * 4 + j;
            v[j] = (idx < NB) ? tot[idx] : 0;
            s += v[j];
        }
        sd[tid] = s;
        __syncthreads();
        for (int off = 1; off < SCT; off <<= 1) {
            int x = (tid >= off) ? sd[tid - off] : 0;
            __syncthreads();
            sd[tid] += x;
            __syncthreads();
        }
        int base = (tid == 0) ? 0 : sd[tid - 1];
#pragma unroll
        for (int j = 0; j < 4; ++j) {
            int idx = tid * 4 + j;
            if (idx < NB) {
                cur[idx] = base + hist_g[blk * NBP + idx];   // contiguous row
                if (blk == 0) bkt_ptr[idx] = base;
                base += v[j];
            }
        }
        if (blk == 0 && tid == 0) bkt_ptr[NB] = E;
        __syncthreads();

        int s0 = blk * chunk, e0 = min(E, s0 + chunk);
        for (int i = s0 + tid; i < e0; i += SCT) {
            int r = rows[i];
            int b = r >> SHIFT;
            unsigned lo = (unsigned)cols[i] | ((unsigned)(r & 31) << 20);
            unsigned hi = __float_as_uint(vals[i]);
            unsigned long long ev = ((unsigned long long)hi << 32) | lo;
            int p = atomicAdd(&cur[b], 1);
            __builtin_nontemporal_store(ev, (unsigned long long*)(edges + p));
        }
        return;
    }

    // ---------------- GEMM path (R15-proven) ----------------
    const int bm  = (blockIdx.x - NBLK) * 128;
    const float alpha = *alpha_p;
    const int wave = tid >> 6;       // 0..15
    const int lane = tid & 63;
    const int l15  = lane & 15;
    const int quad = lane >> 4;
    const int mt   = wave >> 1;      // m-tile 0..7 (16 rows each)
    const int nh   = wave & 1;       // n-half 0..1 (64 cols each)

    half8 a[4];
    {
        const int xrow = bm + mt * 16 + l15;
        const bool ok = xrow < N;
        const float* xp = X + (size_t)xrow * 128 + quad * 8;
#pragma unroll
        for (int k = 0; k < 4; ++k) {
            half8 hv = {};
            if (ok) {
                float4 f0 = *(const float4*)(xp + k * 32);
                float4 f1 = *(const float4*)(xp + k * 32 + 4);
                hv[0] = (_Float16)f0.x; hv[1] = (_Float16)f0.y;
                hv[2] = (_Float16)f0.z; hv[3] = (_Float16)f0.w;
                hv[4] = (_Float16)f1.x; hv[5] = (_Float16)f1.y;
                hv[6] = (_Float16)f1.z; hv[7] = (_Float16)f1.w;
            }
            a[k] = hv;
        }
    }

#pragma unroll
    for (int i = 0; i < 4; ++i) {    // stage W (4x cross-wave reuse)
        int c   = tid + i * 1024;
        int row = c >> 5;
        int coff = (c & 31) * 4;
        float4 f = *(const float4*)(Wr + row * 128 + coff);
        half4 hv = { (_Float16)f.x, (_Float16)f.y, (_Float16)f.z, (_Float16)f.w };
        *(half4*)(&Ws[row * LDK + coff]) = hv;
    }
    __syncthreads();

    floatx4 acc[4] = {};
#pragma unroll
    for (int k = 0; k < 4; ++k) {
#pragma unroll
        for (int n = 0; n < 4; ++n) {
            int nc = nh * 4 + n;
            half8 b = *(const half8*)(&Ws[(nc * 16 + l15) * LDK + k * 32 + quad * 8]);
            acc[n] = __builtin_amdgcn_mfma_f32_16x16x32_f16(a[k], b, acc[n], 0, 0, 0);
        }
    }

#pragma unroll
    for (int n = 0; n < 4; ++n) {
        int col = (nh * 4 + n) * 16 + l15;
        float bcol = bias[col];
#pragma unroll
        for (int r = 0; r < 4; ++r) {
            int row = bm + mt * 16 + quad * 4 + r;
            if (row < N) {
                float v = acc[n][r] + bcol;
                v = (v >= 0.f) ? v : alpha * v;
                out[(size_t)row * 128 + col] = (_Float16)v;
            }
        }
    }
}

// ------- SpMM + GEMM2 fused (R1's proven kernel): per-bucket in-LDS sort,
// register accum, MFMA epilogue. block = 256 thr = 4 waves; bucket = 32 rows;
// wave w accumulates rows [w*8, w*8+8), lane l = cols {2l, 2l+1}. Then temp
// tile -> LDS -> out[32x128] = prelu(T @ W16^T + bias), 16 MFMAs/wave.
__global__ __launch_bounds__(256, 8)
void spmm_fused(const int* __restrict__ bkt_ptr, const uint2* __restrict__ edges,
                const _Float16* __restrict__ h, const _Float16* __restrict__ W16,
                const float* __restrict__ bias, const float* __restrict__ alpha_p,
                float* __restrict__ out, int N)
{
    __shared__ uint2 eS[CAP];
    __shared__ _Float16 T[32 * LDK];
    __shared__ int bins[32], startS[33];

    const int tid  = threadIdx.x;
    const int wave = tid >> 6;
    const int lane = tid & 63;
    const int b    = blockIdx.x;
    const int s0   = bkt_ptr[b], e0 = bkt_ptr[b + 1];

    float acc[8][2] = {};

    for (int base = s0; base < e0; base += CAP) {
        const int n = min(CAP, e0 - base);
        if (tid < 32) bins[tid] = 0;
        __syncthreads();
        uint2 q[4];
#pragma unroll
        for (int u = 0; u < 4; ++u) {
            int i = tid + u * 256;
            if (i < n) {
                q[u] = edges[base + i];
                atomicAdd(&bins[q[u].x >> 20], 1);
            }
        }
        __syncthreads();
        if (tid < 32) {                    // wave-parallel 32-bin inclusive scan
            int x = bins[tid];
#pragma unroll
            for (int off = 1; off < 32; off <<= 1) {
                int y = __shfl_up(x, off);
                if (tid >= off) x += y;
            }
            startS[tid + 1] = x;
            if (tid == 0) startS[0] = 0;
            bins[tid] = x - bins[tid];     // bins becomes running cursor (exclusive)
        }
        __syncthreads();
#pragma unroll
        for (int u = 0; u < 4; ++u) {
            int i = tid + u * 256;
            if (i < n) {
                int p = atomicAdd(&bins[q[u].x >> 20], 1);
                eS[p] = q[u];
            }
        }
        __syncthreads();

#pragma unroll
        for (int j = 0; j < 8; ++j) {
            int r  = wave * 8 + j;
            int rs = startS[r], re = startS[r + 1];
            float a0r = acc[j][0], a1r = acc[j][1];
            int i = rs;
            for (; i + 7 < re; i += 8) {   // deep unroll: 8 gathers in flight
                uint2 q0 = eS[i],     q1 = eS[i + 1], q2 = eS[i + 2], q3 = eS[i + 3];
                uint2 q4 = eS[i + 4], q5 = eS[i + 5], q6 = eS[i + 6], q7 = eS[i + 7];
                half2v v0 = *(const half2v*)(h + (size_t)(q0.x & 0xFFFFF) * 128 + lane * 2);
                half2v v1 = *(const half2v*)(h + (size_t)(q1.x & 0xFFFFF) * 128 + lane * 2);
                half2v v2 = *(const half2v*)(h + (size_t)(q2.x & 0xFFFFF) * 128 + lane * 2);
                half2v v3 = *(const half2v*)(h + (size_t)(q3.x & 0xFFFFF) * 128 + lane * 2);
                half2v v4 = *(const half2v*)(h + (size_t)(q4.x & 0xFFFFF) * 128 + lane * 2);
                half2v v5 = *(const half2v*)(h + (size_t)(q5.x & 0xFFFFF) * 128 + lane * 2);
                half2v v6 = *(const half2v*)(h + (size_t)(q6.x & 0xFFFFF) * 128 + lane * 2);
                half2v v7 = *(const half2v*)(h + (size_t)(q7.x & 0xFFFFF) * 128 + lane * 2);
                float w0 = __uint_as_float(q0.y), w1 = __uint_as_float(q1.y);
                float w2 = __uint_as_float(q2.y), w3 = __uint_as_float(q3.y);
                float w4 = __uint_as_float(q4.y), w5 = __uint_as_float(q5.y);
                float w6 = __uint_as_float(q6.y), w7 = __uint_as_float(q7.y);
                a0r += w0 * (float)v0[0]; a1r += w0 * (float)v0[1];
                a0r += w1 * (float)v1[0]; a1r += w1 * (float)v1[1];
                a0r += w2 * (float)v2[0]; a1r += w2 * (float)v2[1];
                a0r += w3 * (float)v3[0]; a1r += w3 * (float)v3[1];
                a0r += w4 * (float)v4[0]; a1r += w4 * (float)v4[1];
                a0r += w5 * (float)v5[0]; a1r += w5 * (float)v5[1];
                a0r += w6 * (float)v6[0]; a1r += w6 * (float)v6[1];
                a0r += w7 * (float)v7[0]; a1r += w7 * (float)v7[1];
            }
            for (; i + 1 < re; i += 2) {
                uint2 q0 = eS[i], q1 = eS[i + 1];
                half2v v0 = *(const half2v*)(h + (size_t)(q0.x & 0xFFFFF) * 128 + lane * 2);
                half2v v1 = *(const half2v*)(h + (size_t)(q1.x & 0xFFFFF) * 128 + lane * 2);
                float w0 = __uint_as_float(q0.y), w1 = __uint_as_float(q1.y);
                a0r += w0 * (float)v0[0]; a1r += w0 * (float)v0[1];
                a0r += w1 * (float)v1[0]; a1r += w1 * (float)v1[1];
            }
            if (i < re) {
                uint2 q0 = eS[i];
                half2v v0 = *(const half2v*)(h + (size_t)(q0.x & 0xFFFFF) * 128 + lane * 2);
                float w0 = __uint_as_float(q0.y);
                a0r += w0 * (float)v0[0]; a1r += w0 * (float)v0[1];
            }
            acc[j][0] = a0r; acc[j][1] = a1r;
        }
        __syncthreads();   // protect eS before next chunk
    }

    // temp tile -> LDS (f16), row stride LDK breaks MFMA-read conflicts
#pragma unroll
    for (int j = 0; j < 8; ++j) {
        half2v o = { (_Float16)acc[j][0], (_Float16)acc[j][1] };
        *(half2v*)(&T[(wave * 8 + j) * LDK + lane * 2]) = o;
    }
    __syncthreads();

    // GEMM2 epilogue: out[32x128] = prelu(T @ W16^T + bias)
    const float alpha = *alpha_p;
    const int l15  = lane & 15;
    const int quad = lane >> 4;
    floatx4 c[2][2] = {};   // m-tiles {0,16} x n-tiles {wave*2, wave*2+1}
#pragma unroll
    for (int k0 = 0; k0 < 128; k0 += 32) {
        half8 a0 = *(const half8*)(&T[(     l15) * LDK + k0 + quad * 8]);
        half8 a1 = *(const half8*)(&T[(16 + l15) * LDK + k0 + quad * 8]);
#pragma unroll
        for (int nt = 0; nt < 2; ++nt) {
            int nrow = (wave * 2 + nt) * 16 + l15;
            half8 bf = *(const half8*)(W16 + nrow * 128 + k0 + quad * 8);
            c[0][nt] = __builtin_amdgcn_mfma_f32_16x16x32_f16(a0, bf, c[0][nt], 0, 0, 0);
            c[1][nt] = __builtin_amdgcn_mfma_f32_16x16x32_f16(a1, bf, c[1][nt], 0, 0, 0);
        }
    }
    const int row0 = b << SHIFT;
#pragma unroll
    for (int mt = 0; mt < 2; ++mt) {
#pragma unroll
        for (int nt = 0; nt < 2; ++nt) {
            int col = (wave * 2 + nt) * 16 + l15;
            float bcol = bias[col];
#pragma unroll
            for (int r = 0; r < 4; ++r) {
                int row = row0 + mt * 16 + quad * 4 + r;
                if (row < N) {
                    float v = c[mt][nt][r] + bcol;
                    v = (v >= 0.f) ? v : alpha * v;
                    out[(size_t)row * 128 + col] = v;
                }
            }
        }
    }
}

// ---------------- launcher ----------------
static inline size_t align256(size_t x) { return (x + 255) & ~(size_t)255; }

extern "C" void kernel_launch(void* const* d_in, const int* in_sizes, int n_in,
                              void* d_out, int out_size, void* d_ws, size_t ws_size,
                              hipStream_t stream)
{
    const float* AX        = (const float*)d_in[0];
    const int*   A_row     = (const int*)  d_in[1];
    const int*   A_col     = (const int*)  d_in[2];
    const float* A_val     = (const float*)d_in[3];
    const float* Wr_w      = (const float*)d_in[4];
    const float* Wr_b      = (const float*)d_in[5];
    const float* W_w       = (const float*)d_in[6];
    const float* W_b       = (const float*)d_in[7];
    const float* g_alpha   = (const float*)d_in[8];
    const float* act_alpha = (const float*)d_in[9];

    const int N = in_sizes[0] / 128;
    const int E = in_sizes[1];
    const int NB = (N + 31) >> SHIFT;            // 3125
    const int chunk = (E + NBLK - 1) / NBLK;     // 6250

    char* ws = (char*)d_ws;
    size_t off = 0;
    _Float16* h       = (_Float16*)(ws + off); off += align256((size_t)N * 128 * 2);
    uint2*    edges   = (uint2*)   (ws + off); off += align256((size_t)E * 8);
    int*      hist_g  = (int*)     (ws + off); off += align256((size_t)NBLK * NBP * 4);
    int*      tot     = (int*)     (ws + off); off += align256((size_t)NB * 4);
    int*      bkt_ptr = (int*)     (ws + off); off += align256((size_t)(NB + 1) * 4);
    _Float16* W16     = (_Float16*)(ws + off); off += align256((size_t)128 * 128 * 2);
    (void)ws_size; (void)n_in; (void)out_size;

    const int gemmB = (N + 127) / 128;           // 782

    bucket_hist<<<NBLK, SCT, 0, stream>>>(A_row, hist_g, E, chunk, NB, W_w, W16);
    scan1_tile<<<(NB + SCANB - 1) / SCANB, 1024, 0, stream>>>(hist_g, tot, NB);
    scatter_gemm<<<NBLK + gemmB, 1024, 0, stream>>>(A_row, A_col, A_val, tot, hist_g,
                                                    edges, bkt_ptr, E, chunk, NB,
                                                    AX, Wr_w, Wr_b, g_alpha, h, N);
    spmm_fused<<<NB, 256, 0, stream>>>(bkt_ptr, edges, h, W16, W_b, act_alpha,
                                       (float*)d_out, N);
}

// Round 11
// 251.181 us; speedup vs baseline: 1.1029x; 1.1029x over previous
//
#include <hip/hip_runtime.h>
#include <stdint.h>

// GCN layer: out = prelu(W @ segsum(A_val * h[A_col] -> A_row) + b, act_a)
//            h   = prelu(Wr @ AX + br, g_a)
// spmm (R1/R7 kernel) AT its random-line fetch ceiling: ~79us, beyond-L2
// fetch pinned 2.0-2.25 TB/s across 4 structures (R10); h-miss ~165MB ==
// compulsory floor. Failures: R8 global-atomic scatter; R11 threadfence
// scan (device fence = XCD L2 flush/block); R13 64-block scatter; R16
// NONTEMPORAL edge stores (+27us: NT bypasses L2 write-combining, so
// random 8B stores each stream a partial line to DRAM -- NT is only for
// full-line streaming writes). R14 WIN 266.7; R15 WIN 250.2 (GEMM rides
// scatter dispatch; shfl scan).
// R17: revert ONLY the NT store (back to cached store; L2 merges the ~8
// stores per 64B line). Keep R16's sound pieces: hist_g[blk][bucket]
// transposed layout (hist write + scatter cursor-init contiguous; FETCH
// dropped 51MB->3MB confirmed) + scan1_tile LDS transpose scan.

typedef _Float16 half8 __attribute__((ext_vector_type(8)));
typedef _Float16 half4 __attribute__((ext_vector_type(4)));
typedef _Float16 half2v __attribute__((ext_vector_type(2)));
typedef float floatx4 __attribute__((ext_vector_type(4)));

#define LDK 136        // GEMM LDS row stride in halfs: 128 + 8
#define SHIFT 5        // 32 rows per bucket
#define NBMAX 3200     // >= ceil(100000/32) = 3125
#define NBLK 256       // hist/scatter chunks
#define SCT 1024       // hist/scatter threads per block
#define CAP 1024       // LDS edge capacity per sort chunk (max bucket ~650 expected)
#define SCANB 64       // buckets per scan1_tile block
#define NBP 3136       // padded bucket count (49 * 64)

// ---------------- hist: per-chunk bucket histogram ----------------
// Layout hist_g[blk][bucket] -> writeout is a contiguous 12.5KB row.
// Block 0 also converts W fp32 -> f16 (consumed 2 dispatches later).
__global__ __launch_bounds__(SCT)
void bucket_hist(const int* __restrict__ rows, int* __restrict__ hist_g,
                 int E, int chunk, int NB,
                 const float* __restrict__ W, _Float16* __restrict__ W16)
{
    __shared__ int lh[NBMAX];
    int tid = threadIdx.x, blk = blockIdx.x;
    if (blk == 0) {
#pragma unroll
        for (int j = 0; j < 16; ++j) W16[tid + j * 1024] = (_Float16)W[tid + j * 1024];
    }
    for (int i = tid; i < NB; i += SCT) lh[i] = 0;
    __syncthreads();
    int s = blk * chunk, e = min(E, s + chunk);
    for (int i = s + tid; i < e; i += SCT)
        atomicAdd(&lh[rows[i] >> SHIFT], 1);
    __syncthreads();
    for (int b = tid; b < NB; b += SCT)
        hist_g[blk * NBP + b] = lh[b];           // contiguous row write
}

// ---------------- scan1_tile: transpose-in-LDS per-bucket chunk scan -------
// Block handles 64 buckets: loads the 256(chunks) x 64(buckets) tile with
// coalesced row reads, does a segmented exclusive scan down each bucket
// column in LDS, writes back coalesced. tot[b] = bucket total.
__global__ __launch_bounds__(1024)
void scan1_tile(int* __restrict__ hist_g, int* __restrict__ tot, int NB)
{
    __shared__ int tile[NBLK][SCANB + 1];        // 66.6KB, +1 pad vs bank hits
    __shared__ int segsum[SCANB][16];
    const int tid = threadIdx.x;
    const int b0  = blockIdx.x * SCANB;

#pragma unroll
    for (int j = 0; j < 16; ++j) {               // coalesced load
        int lin = tid + j * 1024;
        int r = lin >> 6, c = lin & 63;
        int gb = b0 + c;
        tile[r][c] = (gb < NB) ? hist_g[r * NBP + gb] : 0;
    }
    __syncthreads();

    const int c = tid >> 4, seg = tid & 15;      // 64 buckets x 16 segments
    int s = 0;
#pragma unroll
    for (int k = 0; k < 16; ++k) {               // exclusive within segment
        int r = seg * 16 + k;
        int v = tile[r][c];
        tile[r][c] = s;
        s += v;
    }
    segsum[c][seg] = s;
    __syncthreads();
    if (seg == 0) {                              // scan the 16 segment sums
        int run = 0;
#pragma unroll
        for (int k = 0; k < 16; ++k) { int v = segsum[c][k]; segsum[c][k] = run; run += v; }
        int gb = b0 + c;
        if (gb < NB) tot[gb] = run;              // bucket total
    }
    __syncthreads();
    {
        int base = segsum[c][seg];
#pragma unroll
        for (int k = 0; k < 16; ++k) tile[seg * 16 + k][c] += base;
    }
    __syncthreads();

#pragma unroll
    for (int j = 0; j < 16; ++j) {               // coalesced writeback
        int lin = tid + j * 1024;
        int r = lin >> 6, cc = lin & 63;
        int gb = b0 + cc;
        if (gb < NB) hist_g[r * NBP + gb] = tile[r][cc];
    }
}

// ------ fused scatter + GEMM1 (1024-thr blocks) ----------------------------
// blocks [0,NBLK): scatter with inlined tot-scan (R14-proven); cursor init
// reads a contiguous hist_g row; edge stores CACHED (L2 write-combining).
// blocks [NBLK,NBLK+gemmB): h = prelu(AX@Wr^T+br), 16 waves/block (R15).
__global__ __launch_bounds__(1024, 4)
void scatter_gemm(const int* __restrict__ rows, const int* __restrict__ cols,
                  const float* __restrict__ vals, const int* __restrict__ tot,
                  const int* __restrict__ hist_g, uint2* __restrict__ edges,
                  int* __restrict__ bkt_ptr, int E, int chunk, int NB,
                  const float* __restrict__ X, const float* __restrict__ Wr,
                  const float* __restrict__ bias, const float* __restrict__ alpha_p,
                  _Float16* __restrict__ out, int N)
{
    __shared__ _Float16 Ws[128 * LDK];   // 34.8KB; scatter aliases a prefix
    const int tid = threadIdx.x;

    if (blockIdx.x < NBLK) {
        // ---------------- scatter path ----------------
        int* sd  = (int*)Ws;                     // [SCT]      4KB
        int* cur = (int*)Ws + SCT;               // [NBMAX]   12.8KB
        const int blk = blockIdx.x;

        int v[4]; int s = 0;
#pragma unroll
        for (int j = 0; j < 4; ++j) {
            int idx = tid * 4 + j;
            v[j] = (idx < NB) ? tot[idx] : 0;
            s += v[j];
        }
        sd[tid] = s;
        __syncthreads();
        for (int off = 1; off < SCT; off <<= 1) {
            int x = (tid >= off) ? sd[tid - off] : 0;
            __syncthreads();
            sd[tid] += x;
            __syncthreads();
        }
        int base = (tid == 0) ? 0 : sd[tid - 1];
#pragma unroll
        for (int j = 0; j < 4; ++j) {
            int idx = tid * 4 + j;
            if (idx < NB) {
                cur[idx] = base + hist_g[blk * NBP + idx];   // contiguous row
                if (blk == 0) bkt_ptr[idx] = base;
                base += v[j];
            }
        }
        if (blk == 0 && tid == 0) bkt_ptr[NB] = E;
        __syncthreads();

        int s0 = blk * chunk, e0 = min(E, s0 + chunk);
        for (int i = s0 + tid; i < e0; i += SCT) {
            int r = rows[i];
            int b = r >> SHIFT;
            uint2 ed;
            ed.x = (unsigned)cols[i] | ((unsigned)(r & 31) << 20);
            ed.y = __float_as_uint(vals[i]);
            int p = atomicAdd(&cur[b], 1);
            edges[p] = ed;                        // cached store: L2 merges lines
        }
        return;
    }

    // ---------------- GEMM path (R15-proven) ----------------
    const int bm  = (blockIdx.x - NBLK) * 128;
    const float alpha = *alpha_p;
    const int wave = tid >> 6;       // 0..15
    const int lane = tid & 63;
    const int l15  = lane & 15;
    const int quad = lane >> 4;
    const int mt   = wave >> 1;      // m-tile 0..7 (16 rows each)
    const int nh   = wave & 1;       // n-half 0..1 (64 cols each)

    half8 a[4];
    {
        const int xrow = bm + mt * 16 + l15;
        const bool ok = xrow < N;
        const float* xp = X + (size_t)xrow * 128 + quad * 8;
#pragma unroll
        for (int k = 0; k < 4; ++k) {
            half8 hv = {};
            if (ok) {
                float4 f0 = *(const float4*)(xp + k * 32);
                float4 f1 = *(const float4*)(xp + k * 32 + 4);
                hv[0] = (_Float16)f0.x; hv[1] = (_Float16)f0.y;
                hv[2] = (_Float16)f0.z; hv[3] = (_Float16)f0.w;
                hv[4] = (_Float16)f1.x; hv[5] = (_Float16)f1.y;
                hv[6] = (_Float16)f1.z; hv[7] = (_Float16)f1.w;
            }
            a[k] = hv;
        }
    }

#pragma unroll
    for (int i = 0; i < 4; ++i) {    // stage W (4x cross-wave reuse)
        int c   = tid + i * 1024;
        int row = c >> 5;
        int coff = (c & 31) * 4;
        float4 f = *(const float4*)(Wr + row * 128 + coff);
        half4 hv = { (_Float16)f.x, (_Float16)f.y, (_Float16)f.z, (_Float16)f.w };
        *(half4*)(&Ws[row * LDK + coff]) = hv;
    }
    __syncthreads();

    floatx4 acc[4] = {};
#pragma unroll
    for (int k = 0; k < 4; ++k) {
#pragma unroll
        for (int n = 0; n < 4; ++n) {
            int nc = nh * 4 + n;
            half8 b = *(const half8*)(&Ws[(nc * 16 + l15) * LDK + k * 32 + quad * 8]);
            acc[n] = __builtin_amdgcn_mfma_f32_16x16x32_f16(a[k], b, acc[n], 0, 0, 0);
        }
    }

#pragma unroll
    for (int n = 0; n < 4; ++n) {
        int col = (nh * 4 + n) * 16 + l15;
        float bcol = bias[col];
#pragma unroll
        for (int r = 0; r < 4; ++r) {
            int row = bm + mt * 16 + quad * 4 + r;
            if (row < N) {
                float v = acc[n][r] + bcol;
                v = (v >= 0.f) ? v : alpha * v;
                out[(size_t)row * 128 + col] = (_Float16)v;
            }
        }
    }
}

// ------- SpMM + GEMM2 fused (R1's proven kernel): per-bucket in-LDS sort,
// register accum, MFMA epilogue. block = 256 thr = 4 waves; bucket = 32 rows;
// wave w accumulates rows [w*8, w*8+8), lane l = cols {2l, 2l+1}. Then temp
// tile -> LDS -> out[32x128] = prelu(T @ W16^T + bias), 16 MFMAs/wave.
__global__ __launch_bounds__(256, 8)
void spmm_fused(const int* __restrict__ bkt_ptr, const uint2* __restrict__ edges,
                const _Float16* __restrict__ h, const _Float16* __restrict__ W16,
                const float* __restrict__ bias, const float* __restrict__ alpha_p,
                float* __restrict__ out, int N)
{
    __shared__ uint2 eS[CAP];
    __shared__ _Float16 T[32 * LDK];
    __shared__ int bins[32], startS[33];

    const int tid  = threadIdx.x;
    const int wave = tid >> 6;
    const int lane = tid & 63;
    const int b    = blockIdx.x;
    const int s0   = bkt_ptr[b], e0 = bkt_ptr[b + 1];

    float acc[8][2] = {};

    for (int base = s0; base < e0; base += CAP) {
        const int n = min(CAP, e0 - base);
        if (tid < 32) bins[tid] = 0;
        __syncthreads();
        uint2 q[4];
#pragma unroll
        for (int u = 0; u < 4; ++u) {
            int i = tid + u * 256;
            if (i < n) {
                q[u] = edges[base + i];
                atomicAdd(&bins[q[u].x >> 20], 1);
            }
        }
        __syncthreads();
        if (tid < 32) {                    // wave-parallel 32-bin inclusive scan
            int x = bins[tid];
#pragma unroll
            for (int off = 1; off < 32; off <<= 1) {
                int y = __shfl_up(x, off);
                if (tid >= off) x += y;
            }
            startS[tid + 1] = x;
            if (tid == 0) startS[0] = 0;
            bins[tid] = x - bins[tid];     // bins becomes running cursor (exclusive)
        }
        __syncthreads();
#pragma unroll
        for (int u = 0; u < 4; ++u) {
            int i = tid + u * 256;
            if (i < n) {
                int p = atomicAdd(&bins[q[u].x >> 20], 1);
                eS[p] = q[u];
            }
        }
        __syncthreads();

#pragma unroll
        for (int j = 0; j < 8; ++j) {
            int r  = wave * 8 + j;
            int rs = startS[r], re = startS[r + 1];
            float a0r = acc[j][0], a1r = acc[j][1];
            int i = rs;
            for (; i + 7 < re; i += 8) {   // deep unroll: 8 gathers in flight
                uint2 q0 = eS[i],     q1 = eS[i + 1], q2 = eS[i + 2], q3 = eS[i + 3];
                uint2 q4 = eS[i + 4], q5 = eS[i + 5], q6 = eS[i + 6], q7 = eS[i + 7];
                half2v v0 = *(const half2v*)(h + (size_t)(q0.x & 0xFFFFF) * 128 + lane * 2);
                half2v v1 = *(const half2v*)(h + (size_t)(q1.x & 0xFFFFF) * 128 + lane * 2);
                half2v v2 = *(const half2v*)(h + (size_t)(q2.x & 0xFFFFF) * 128 + lane * 2);
                half2v v3 = *(const half2v*)(h + (size_t)(q3.x & 0xFFFFF) * 128 + lane * 2);
                half2v v4 = *(const half2v*)(h + (size_t)(q4.x & 0xFFFFF) * 128 + lane * 2);
                half2v v5 = *(const half2v*)(h + (size_t)(q5.x & 0xFFFFF) * 128 + lane * 2);
                half2v v6 = *(const half2v*)(h + (size_t)(q6.x & 0xFFFFF) * 128 + lane * 2);
                half2v v7 = *(const half2v*)(h + (size_t)(q7.x & 0xFFFFF) * 128 + lane * 2);
                float w0 = __uint_as_float(q0.y), w1 = __uint_as_float(q1.y);
                float w2 = __uint_as_float(q2.y), w3 = __uint_as_float(q3.y);
                float w4 = __uint_as_float(q4.y), w5 = __uint_as_float(q5.y);
                float w6 = __uint_as_float(q6.y), w7 = __uint_as_float(q7.y);
                a0r += w0 * (float)v0[0]; a1r += w0 * (float)v0[1];
                a0r += w1 * (float)v1[0]; a1r += w1 * (float)v1[1];
                a0r += w2 * (float)v2[0]; a1r += w2 * (float)v2[1];
                a0r += w3 * (float)v3[0]; a1r += w3 * (float)v3[1];
                a0r += w4 * (float)v4[0]; a1r += w4 * (float)v4[1];
                a0r += w5 * (float)v5[0]; a1r += w5 * (float)v5[1];
                a0r += w6 * (float)v6[0]; a1r += w6 * (float)v6[1];
                a0r += w7 * (float)v7[0]; a1r += w7 * (float)v7[1];
            }
            for (; i + 1 < re; i += 2) {
                uint2 q0 = eS[i], q1 = eS[i + 1];
                half2v v0 = *(const half2v*)(h + (size_t)(q0.x & 0xFFFFF) * 128 + lane * 2);
                half2v v1 = *(const half2v*)(h + (size_t)(q1.x & 0xFFFFF) * 128 + lane * 2);
                float w0 = __uint_as_float(q0.y), w1 = __uint_as_float(q1.y);
                a0r += w0 * (float)v0[0]; a1r += w0 * (float)v0[1];
                a0r += w1 * (float)v1[0]; a1r += w1 * (float)v1[1];
            }
            if (i < re) {
                uint2 q0 = eS[i];
                half2v v0 = *(const half2v*)(h + (size_t)(q0.x & 0xFFFFF) * 128 + lane * 2);
                float w0 = __uint_as_float(q0.y);
                a0r += w0 * (float)v0[0]; a1r += w0 * (float)v0[1];
            }
            acc[j][0] = a0r; acc[j][1] = a1r;
        }
        __syncthreads();   // protect eS before next chunk
    }

    // temp tile -> LDS (f16), row stride LDK breaks MFMA-read conflicts
#pragma unroll
    for (int j = 0; j < 8; ++j) {
        half2v o = { (_Float16)acc[j][0], (_Float16)acc[j][1] };
        *(half2v*)(&T[(wave * 8 + j) * LDK + lane * 2]) = o;
    }
    __syncthreads();

    // GEMM2 epilogue: out[32x128] = prelu(T @ W16^T + bias)
    const float alpha = *alpha_p;
    const int l15  = lane & 15;
    const int quad = lane >> 4;
    floatx4 c[2][2] = {};   // m-tiles {0,16} x n-tiles {wave*2, wave*2+1}
#pragma unroll
    for (int k0 = 0; k0 < 128; k0 += 32) {
        half8 a0 = *(const half8*)(&T[(     l15) * LDK + k0 + quad * 8]);
        half8 a1 = *(const half8*)(&T[(16 + l15) * LDK + k0 + quad * 8]);
#pragma unroll
        for (int nt = 0; nt < 2; ++nt) {
            int nrow = (wave * 2 + nt) * 16 + l15;
            half8 bf = *(const half8*)(W16 + nrow * 128 + k0 + quad * 8);
            c[0][nt] = __builtin_amdgcn_mfma_f32_16x16x32_f16(a0, bf, c[0][nt], 0, 0, 0);
            c[1][nt] = __builtin_amdgcn_mfma_f32_16x16x32_f16(a1, bf, c[1][nt], 0, 0, 0);
        }
    }
    const int row0 = b << SHIFT;
#pragma unroll
    for (int mt = 0; mt < 2; ++mt) {
#pragma unroll
        for (int nt = 0; nt < 2; ++nt) {
            int col = (wave * 2 + nt) * 16 + l15;
            float bcol = bias[col];
#pragma unroll
            for (int r = 0; r < 4; ++r) {
                int row = row0 + mt * 16 + quad * 4 + r;
                if (row < N) {
                    float v = c[mt][nt][r] + bcol;
                    v = (v >= 0.f) ? v : alpha * v;
                    out[(size_t)row * 128 + col] = v;
                }
            }
        }
    }
}

// ---------------- launcher ----------------
static inline size_t align256(size_t x) { return (x + 255) & ~(size_t)255; }

extern "C" void kernel_launch(void* const* d_in, const int* in_sizes, int n_in,
                              void* d_out, int out_size, void* d_ws, size_t ws_size,
                              hipStream_t stream)
{
    const float* AX        = (const float*)d_in[0];
    const int*   A_row     = (const int*)  d_in[1];
    const int*   A_col     = (const int*)  d_in[2];
    const float* A_val     = (const float*)d_in[3];
    const float* Wr_w      = (const float*)d_in[4];
    const float* Wr_b      = (const float*)d_in[5];
    const float* W_w       = (const float*)d_in[6];
    const float* W_b       = (const float*)d_in[7];
    const float* g_alpha   = (const float*)d_in[8];
    const float* act_alpha = (const float*)d_in[9];

    const int N = in_sizes[0] / 128;
    const int E = in_sizes[1];
    const int NB = (N + 31) >> SHIFT;            // 3125
    const int chunk = (E + NBLK - 1) / NBLK;     // 6250

    char* ws = (char*)d_ws;
    size_t off = 0;
    _Float16* h       = (_Float16*)(ws + off); off += align256((size_t)N * 128 * 2);
    uint2*    edges   = (uint2*)   (ws + off); off += align256((size_t)E * 8);
    int*      hist_g  = (int*)     (ws + off); off += align256((size_t)NBLK * NBP * 4);
    int*      tot     = (int*)     (ws + off); off += align256((size_t)NB * 4);
    int*      bkt_ptr = (int*)     (ws + off); off += align256((size_t)(NB + 1) * 4);
    _Float16* W16     = (_Float16*)(ws + off); off += align256((size_t)128 * 128 * 2);
    (void)ws_size; (void)n_in; (void)out_size;

    const int gemmB = (N + 127) / 128;           // 782

    bucket_hist<<<NBLK, SCT, 0, stream>>>(A_row, hist_g, E, chunk, NB, W_w, W16);
    scan1_tile<<<(NB + SCANB - 1) / SCANB, 1024, 0, stream>>>(hist_g, tot, NB);
    scatter_gemm<<<NBLK + gemmB, 1024, 0, stream>>>(A_row, A_col, A_val, tot, hist_g,
                                                    edges, bkt_ptr, E, chunk, NB,
                                                    AX, Wr_w, Wr_b, g_alpha, h, N);
    spmm_fused<<<NB, 256, 0, stream>>>(bkt_ptr, edges, h, W16, W_b, act_alpha,
                                       (float*)d_out, N);
}

// Round 12
// 237.098 us; speedup vs baseline: 1.1684x; 1.0594x over previous
//
#include <hip/hip_runtime.h>
#include <stdint.h>

// GCN layer: out = prelu(W @ segsum(A_val * h[A_col] -> A_row) + b, act_a)
//            h   = prelu(Wr @ AX + br, g_a)
// spmm (R1/R7 kernel) AT its random-line fetch ceiling: ~80us, beyond-L2
// fetch pinned 2.0-2.25 TB/s across 4 structures (R10); h-miss ~165MB ==
// compulsory floor. Failures: R8 PER-EDGE global-atomic scatter (145us);
// R11 threadfence scan (device fence = XCD L2 flush/block); R13 64-block
// scatter; R16 NT stores (+27us: NT defeats L2 write-combining on sub-line
// stores). R14 WIN 266.7; R15 WIN 250.2; R17 = R15 (transpose layout
// neutral -> strided cursor reads were already L2-hidden).
// R18: budget audit shows kernels ~155-175us vs total 250 -> ~75-95us is
// dispatch overhead (4 launches + drains). Restructure to TWO dispatches:
//  - hist & scan dispatches DELETED. Fixed-stride buckets (CAP_G=1024,
//    R8-proven numerically: nondet intra-bucket order passed) + per-
//    (block,bucket) RANGE RESERVATION: LDS hist of own chunk (proven),
//    ONE global atomicAdd per non-empty bucket (~690K total, reserves ~2
//    slots each; R8's failure was 1.6M PER-EDGE atomics), LDS cursors,
//    cached stores (proven pattern).
//  - Pipeline: memset(12.5KB) -> [scatter || GEMM] -> [spmm].
//  - spmm: s0 = b<<10, count = min(cnt[b], 1024); else byte-identical.

typedef _Float16 half8 __attribute__((ext_vector_type(8)));
typedef _Float16 half4 __attribute__((ext_vector_type(4)));
typedef _Float16 half2v __attribute__((ext_vector_type(2)));
typedef float floatx4 __attribute__((ext_vector_type(4)));

#define LDK 136        // GEMM LDS row stride in halfs: 128 + 8
#define SHIFT 5        // 32 rows per bucket
#define NBMAX 3200     // >= ceil(100000/32) = 3125
#define NBLK 256       // scatter chunks
#define CAP 1024       // bucket stride / LDS sort window (max bucket ~650)

// ------ fused scatter + GEMM1 (1024-thr blocks) ----------------------------
// blocks [0,NBLK): chunk-local LDS hist -> per-bucket global range-reserve
// (cnt pre-zeroed by hipMemsetAsync) -> LDS-cursor scatter, cached stores.
// blocks [NBLK,NBLK+gemmB): h = prelu(AX@Wr^T+br), 16 waves (R15-proven);
// GEMM block 0 also converts W fp32->f16 for spmm.
__global__ __launch_bounds__(1024, 4)
void scatter_gemm(const int* __restrict__ rows, const int* __restrict__ cols,
                  const float* __restrict__ vals, int* __restrict__ cnt,
                  uint2* __restrict__ edges, int E, int chunk, int NB,
                  const float* __restrict__ X, const float* __restrict__ Wr,
                  const float* __restrict__ bias, const float* __restrict__ alpha_p,
                  _Float16* __restrict__ out, int N,
                  const float* __restrict__ W, _Float16* __restrict__ W16)
{
    __shared__ _Float16 Ws[128 * LDK];   // 34.8KB; scatter aliases a prefix
    const int tid = threadIdx.x;

    if (blockIdx.x < NBLK) {
        // ---------------- scatter path ----------------
        int* lh = (int*)Ws;                      // [NBMAX] counts -> cursors
        const int blk = blockIdx.x;
        for (int i = tid; i < NB; i += 1024) lh[i] = 0;
        __syncthreads();
        const int s0 = blk * chunk, e0 = min(E, s0 + chunk);
        for (int i = s0 + tid; i < e0; i += 1024)
            atomicAdd(&lh[rows[i] >> SHIFT], 1);
        __syncthreads();
        for (int b = tid; b < NB; b += 1024) {   // range-reserve: 1 atomic/bucket
            int c = lh[b];
            lh[b] = c ? (b << 10) + atomicAdd(&cnt[b], c) : 0;
        }
        __syncthreads();
        for (int i = s0 + tid; i < e0; i += 1024) {
            int r = rows[i];
            int b = r >> SHIFT;
            uint2 ed;
            ed.x = (unsigned)cols[i] | ((unsigned)(r & 31) << 20);
            ed.y = __float_as_uint(vals[i]);
            int p = atomicAdd(&lh[b], 1);        // LDS cursor = absolute slot
            if (p < ((b + 1) << 10)) edges[p] = ed;   // overflow guard (+22sigma)
        }
        return;
    }

    // ---------------- GEMM path (R15-proven 16-wave) ----------------
    const int bm  = (blockIdx.x - NBLK) * 128;
    const float alpha = *alpha_p;
    const int wave = tid >> 6;       // 0..15
    const int lane = tid & 63;
    const int l15  = lane & 15;
    const int quad = lane >> 4;
    const int mt   = wave >> 1;      // m-tile 0..7 (16 rows each)
    const int nh   = wave & 1;       // n-half 0..1 (64 cols each)

    if (blockIdx.x == NBLK) {        // W fp32 -> f16 (consumed by spmm, next dispatch)
#pragma unroll
        for (int j = 0; j < 16; ++j) W16[tid + j * 1024] = (_Float16)W[tid + j * 1024];
    }

    half8 a[4];
    {
        const int xrow = bm + mt * 16 + l15;
        const bool ok = xrow < N;
        const float* xp = X + (size_t)xrow * 128 + quad * 8;
#pragma unroll
        for (int k = 0; k < 4; ++k) {
            half8 hv = {};
            if (ok) {
                float4 f0 = *(const float4*)(xp + k * 32);
                float4 f1 = *(const float4*)(xp + k * 32 + 4);
                hv[0] = (_Float16)f0.x; hv[1] = (_Float16)f0.y;
                hv[2] = (_Float16)f0.z; hv[3] = (_Float16)f0.w;
                hv[4] = (_Float16)f1.x; hv[5] = (_Float16)f1.y;
                hv[6] = (_Float16)f1.z; hv[7] = (_Float16)f1.w;
            }
            a[k] = hv;
        }
    }

#pragma unroll
    for (int i = 0; i < 4; ++i) {    // stage W (4x cross-wave reuse)
        int c   = tid + i * 1024;
        int row = c >> 5;
        int coff = (c & 31) * 4;
        float4 f = *(const float4*)(Wr + row * 128 + coff);
        half4 hv = { (_Float16)f.x, (_Float16)f.y, (_Float16)f.z, (_Float16)f.w };
        *(half4*)(&Ws[row * LDK + coff]) = hv;
    }
    __syncthreads();

    floatx4 acc[4] = {};
#pragma unroll
    for (int k = 0; k < 4; ++k) {
#pragma unroll
        for (int n = 0; n < 4; ++n) {
            int nc = nh * 4 + n;
            half8 b = *(const half8*)(&Ws[(nc * 16 + l15) * LDK + k * 32 + quad * 8]);
            acc[n] = __builtin_amdgcn_mfma_f32_16x16x32_f16(a[k], b, acc[n], 0, 0, 0);
        }
    }

#pragma unroll
    for (int n = 0; n < 4; ++n) {
        int col = (nh * 4 + n) * 16 + l15;
        float bcol = bias[col];
#pragma unroll
        for (int r = 0; r < 4; ++r) {
            int row = bm + mt * 16 + quad * 4 + r;
            if (row < N) {
                float v = acc[n][r] + bcol;
                v = (v >= 0.f) ? v : alpha * v;
                out[(size_t)row * 128 + col] = (_Float16)v;
            }
        }
    }
}

// ------- SpMM + GEMM2 fused (R1's proven kernel): per-bucket in-LDS sort,
// register accum, MFMA epilogue. block = 256 thr = 4 waves; bucket = 32 rows;
// wave w accumulates rows [w*8, w*8+8), lane l = cols {2l, 2l+1}. Then temp
// tile -> LDS -> out[32x128] = prelu(T @ W16^T + bias), 16 MFMAs/wave.
// R18: bucket range = [b<<10, b<<10 + min(cnt[b], CAP)).
__global__ __launch_bounds__(256, 8)
void spmm_fused(const int* __restrict__ cnt, const uint2* __restrict__ edges,
                const _Float16* __restrict__ h, const _Float16* __restrict__ W16,
                const float* __restrict__ bias, const float* __restrict__ alpha_p,
                float* __restrict__ out, int N)
{
    __shared__ uint2 eS[CAP];
    __shared__ _Float16 T[32 * LDK];
    __shared__ int bins[32], startS[33];

    const int tid  = threadIdx.x;
    const int wave = tid >> 6;
    const int lane = tid & 63;
    const int b    = blockIdx.x;
    const int s0   = b << 10;
    const int e0   = s0 + min(cnt[b], CAP);

    float acc[8][2] = {};

    for (int base = s0; base < e0; base += CAP) {
        const int n = min(CAP, e0 - base);
        if (tid < 32) bins[tid] = 0;
        __syncthreads();
        uint2 q[4];
#pragma unroll
        for (int u = 0; u < 4; ++u) {
            int i = tid + u * 256;
            if (i < n) {
                q[u] = edges[base + i];
                atomicAdd(&bins[q[u].x >> 20], 1);
            }
        }
        __syncthreads();
        if (tid < 32) {                    // wave-parallel 32-bin inclusive scan
            int x = bins[tid];
#pragma unroll
            for (int off = 1; off < 32; off <<= 1) {
                int y = __shfl_up(x, off);
                if (tid >= off) x += y;
            }
            startS[tid + 1] = x;
            if (tid == 0) startS[0] = 0;
            bins[tid] = x - bins[tid];     // bins becomes running cursor (exclusive)
        }
        __syncthreads();
#pragma unroll
        for (int u = 0; u < 4; ++u) {
            int i = tid + u * 256;
            if (i < n) {
                int p = atomicAdd(&bins[q[u].x >> 20], 1);
                eS[p] = q[u];
            }
        }
        __syncthreads();

#pragma unroll
        for (int j = 0; j < 8; ++j) {
            int r  = wave * 8 + j;
            int rs = startS[r], re = startS[r + 1];
            float a0r = acc[j][0], a1r = acc[j][1];
            int i = rs;
            for (; i + 7 < re; i += 8) {   // deep unroll: 8 gathers in flight
                uint2 q0 = eS[i],     q1 = eS[i + 1], q2 = eS[i + 2], q3 = eS[i + 3];
                uint2 q4 = eS[i + 4], q5 = eS[i + 5], q6 = eS[i + 6], q7 = eS[i + 7];
                half2v v0 = *(const half2v*)(h + (size_t)(q0.x & 0xFFFFF) * 128 + lane * 2);
                half2v v1 = *(const half2v*)(h + (size_t)(q1.x & 0xFFFFF) * 128 + lane * 2);
                half2v v2 = *(const half2v*)(h + (size_t)(q2.x & 0xFFFFF) * 128 + lane * 2);
                half2v v3 = *(const half2v*)(h + (size_t)(q3.x & 0xFFFFF) * 128 + lane * 2);
                half2v v4 = *(const half2v*)(h + (size_t)(q4.x & 0xFFFFF) * 128 + lane * 2);
                half2v v5 = *(const half2v*)(h + (size_t)(q5.x & 0xFFFFF) * 128 + lane * 2);
                half2v v6 = *(const half2v*)(h + (size_t)(q6.x & 0xFFFFF) * 128 + lane * 2);
                half2v v7 = *(const half2v*)(h + (size_t)(q7.x & 0xFFFFF) * 128 + lane * 2);
                float w0 = __uint_as_float(q0.y), w1 = __uint_as_float(q1.y);
                float w2 = __uint_as_float(q2.y), w3 = __uint_as_float(q3.y);
                float w4 = __uint_as_float(q4.y), w5 = __uint_as_float(q5.y);
                float w6 = __uint_as_float(q6.y), w7 = __uint_as_float(q7.y);
                a0r += w0 * (float)v0[0]; a1r += w0 * (float)v0[1];
                a0r += w1 * (float)v1[0]; a1r += w1 * (float)v1[1];
                a0r += w2 * (float)v2[0]; a1r += w2 * (float)v2[1];
                a0r += w3 * (float)v3[0]; a1r += w3 * (float)v3[1];
                a0r += w4 * (float)v4[0]; a1r += w4 * (float)v4[1];
                a0r += w5 * (float)v5[0]; a1r += w5 * (float)v5[1];
                a0r += w6 * (float)v6[0]; a1r += w6 * (float)v6[1];
                a0r += w7 * (float)v7[0]; a1r += w7 * (float)v7[1];
            }
            for (; i + 1 < re; i += 2) {
                uint2 q0 = eS[i], q1 = eS[i + 1];
                half2v v0 = *(const half2v*)(h + (size_t)(q0.x & 0xFFFFF) * 128 + lane * 2);
                half2v v1 = *(const half2v*)(h + (size_t)(q1.x & 0xFFFFF) * 128 + lane * 2);
                float w0 = __uint_as_float(q0.y), w1 = __uint_as_float(q1.y);
                a0r += w0 * (float)v0[0]; a1r += w0 * (float)v0[1];
                a0r += w1 * (float)v1[0]; a1r += w1 * (float)v1[1];
            }
            if (i < re) {
                uint2 q0 = eS[i];
                half2v v0 = *(const half2v*)(h + (size_t)(q0.x & 0xFFFFF) * 128 + lane * 2);
                float w0 = __uint_as_float(q0.y);
                a0r += w0 * (float)v0[0]; a1r += w0 * (float)v0[1];
            }
            acc[j][0] = a0r; acc[j][1] = a1r;
        }
        __syncthreads();   // protect eS before next chunk
    }

    // temp tile -> LDS (f16), row stride LDK breaks MFMA-read conflicts
#pragma unroll
    for (int j = 0; j < 8; ++j) {
        half2v o = { (_Float16)acc[j][0], (_Float16)acc[j][1] };
        *(half2v*)(&T[(wave * 8 + j) * LDK + lane * 2]) = o;
    }
    __syncthreads();

    // GEMM2 epilogue: out[32x128] = prelu(T @ W16^T + bias)
    const float alpha = *alpha_p;
    const int l15  = lane & 15;
    const int quad = lane >> 4;
    floatx4 c[2][2] = {};   // m-tiles {0,16} x n-tiles {wave*2, wave*2+1}
#pragma unroll
    for (int k0 = 0; k0 < 128; k0 += 32) {
        half8 a0 = *(const half8*)(&T[(     l15) * LDK + k0 + quad * 8]);
        half8 a1 = *(const half8*)(&T[(16 + l15) * LDK + k0 + quad * 8]);
#pragma unroll
        for (int nt = 0; nt < 2; ++nt) {
            int nrow = (wave * 2 + nt) * 16 + l15;
            half8 bf = *(const half8*)(W16 + nrow * 128 + k0 + quad * 8);
            c[0][nt] = __builtin_amdgcn_mfma_f32_16x16x32_f16(a0, bf, c[0][nt], 0, 0, 0);
            c[1][nt] = __builtin_amdgcn_mfma_f32_16x16x32_f16(a1, bf, c[1][nt], 0, 0, 0);
        }
    }
    const int row0 = b << SHIFT;
#pragma unroll
    for (int mt = 0; mt < 2; ++mt) {
#pragma unroll
        for (int nt = 0; nt < 2; ++nt) {
            int col = (wave * 2 + nt) * 16 + l15;
            float bcol = bias[col];
#pragma unroll
            for (int r = 0; r < 4; ++r) {
                int row = row0 + mt * 16 + quad * 4 + r;
                if (row < N) {
                    float v = c[mt][nt][r] + bcol;
                    v = (v >= 0.f) ? v : alpha * v;
                    out[(size_t)row * 128 + col] = v;
                }
            }
        }
    }
}

// ---------------- launcher ----------------
static inline size_t align256(size_t x) { return (x + 255) & ~(size_t)255; }

extern "C" void kernel_launch(void* const* d_in, const int* in_sizes, int n_in,
                              void* d_out, int out_size, void* d_ws, size_t ws_size,
                              hipStream_t stream)
{
    const float* AX        = (const float*)d_in[0];
    const int*   A_row     = (const int*)  d_in[1];
    const int*   A_col     = (const int*)  d_in[2];
    const float* A_val     = (const float*)d_in[3];
    const float* Wr_w      = (const float*)d_in[4];
    const float* Wr_b      = (const float*)d_in[5];
    const float* W_w       = (const float*)d_in[6];
    const float* W_b       = (const float*)d_in[7];
    const float* g_alpha   = (const float*)d_in[8];
    const float* act_alpha = (const float*)d_in[9];

    const int N = in_sizes[0] / 128;
    const int E = in_sizes[1];
    const int NB = (N + 31) >> SHIFT;            // 3125
    const int chunk = (E + NBLK - 1) / NBLK;     // 6250

    char* ws = (char*)d_ws;
    size_t off = 0;
    _Float16* h     = (_Float16*)(ws + off); off += align256((size_t)N * 128 * 2);
    uint2*    edges = (uint2*)   (ws + off); off += align256((size_t)NB * CAP * 8);
    int*      cnt   = (int*)     (ws + off); off += align256((size_t)NB * 4);
    _Float16* W16   = (_Float16*)(ws + off); off += align256((size_t)128 * 128 * 2);
    (void)ws_size; (void)n_in; (void)out_size;

    const int gemmB = (N + 127) / 128;           // 782

    hipMemsetAsync(cnt, 0, (size_t)NB * 4, stream);
    scatter_gemm<<<NBLK + gemmB, 1024, 0, stream>>>(A_row, A_col, A_val, cnt, edges,
                                                    E, chunk, NB,
                                                    AX, Wr_w, Wr_b, g_alpha, h, N,
                                                    W_w, W16);
    spmm_fused<<<NB, 256, 0, stream>>>(cnt, edges, h, W16, W_b, act_alpha,
                                       (float*)d_out, N);
}